// Round 3
// baseline (1311.128 us; speedup 1.0000x reference)
//
#include <hip/hip_runtime.h>

// EncoderSRNN: T=256 steps, B=128, HDIM=EDIM=256, SSZ=64, SDIM=64, SDEPTH=2, NACT=3
#define T_STEPS 256
#define BATCH 128

// ws float offsets (transposed weights + combined bias)
#define WEHT_OFF 0         // [e][h] 256x256
#define WHHT_OFF 65536     // [e][h] 256x256
#define WSHT_OFF 131072    // [j][h] 128x256
#define WHST_OFF 163840    // [e][s] 256x64
#define WSUT_OFF 180224    // [j][s] 128x64
#define BC_OFF   188416    // bc[h] = b_eh+b_hh+b_sh

#define HID_OFF   8388608
#define STACK_OFF 8421376
#define ACTS_OFF  8945664

// ---------------- kernel 0: transpose weights into ws, fold biases ----------
__global__ __launch_bounds__(256) void prep_kernel(
    const float* __restrict__ W_hh, const float* __restrict__ b_hh,
    const float* __restrict__ W_eh, const float* __restrict__ b_eh,
    const float* __restrict__ W_sh, const float* __restrict__ b_sh,
    const float* __restrict__ W_hs, const float* __restrict__ W_su,
    float* __restrict__ ws)
{
    int idx = blockIdx.x * 256 + threadIdx.x;
    if (idx < 65536) {                       // W_ehT[e][h] = W_eh[h][e]
        ws[WEHT_OFF + idx] = W_eh[(idx & 255) * 256 + (idx >> 8)];
    } else if (idx < 131072) {               // W_hhT
        int k = idx - 65536;
        ws[WHHT_OFF + k] = W_hh[(k & 255) * 256 + (k >> 8)];
    } else if (idx < 163840) {               // W_shT[j][h] = W_sh[h][j]
        int k = idx - 131072;
        ws[WSHT_OFF + k] = W_sh[(k & 255) * 128 + (k >> 8)];
    } else if (idx < 180224) {               // W_hsT[e][s] = W_hs[s][e]
        int k = idx - 163840;
        ws[WHST_OFF + k] = W_hs[(k & 63) * 256 + (k >> 6)];
    } else if (idx < 188416) {               // W_suT[j][s] = W_su[s][j]
        int k = idx - 180224;
        ws[WSUT_OFF + k] = W_su[(k & 63) * 128 + (k >> 6)];
    } else if (idx < 188672) {
        int k = idx - 188416;
        ws[BC_OFF + k] = b_eh[k] + b_hh[k] + b_sh[k];
    }
}

// ---------------- kernel 1: ex[t,b,h] = emb_W[tok]@W_eh.T + bc  -------------
__global__ __launch_bounds__(256) void ex_gemm(
    const int* __restrict__ tokens, const float* __restrict__ emb_W,
    const float* __restrict__ ws, float* __restrict__ outp)
{
    __shared__ __align__(16) float aT[64 * 40];
    __shared__ int tok[32];
    const int t = threadIdx.x;
    const int R0 = blockIdx.x * 32;
    if (t < 32) tok[t] = tokens[R0 + t];
    __syncthreads();

    float acc[32];
#pragma unroll
    for (int r = 0; r < 32; r++) acc[r] = 0.f;

    for (int e0 = 0; e0 < 256; e0 += 64) {
        {
            int r = t >> 3, seg = t & 7;
            const float* src = emb_W + (size_t)tok[r] * 256 + e0 + seg * 8;
            float4 v0 = *(const float4*)(src);
            float4 v1 = *(const float4*)(src + 4);
            int eb = seg * 8;
            aT[(eb + 0) * 40 + r] = v0.x; aT[(eb + 1) * 40 + r] = v0.y;
            aT[(eb + 2) * 40 + r] = v0.z; aT[(eb + 3) * 40 + r] = v0.w;
            aT[(eb + 4) * 40 + r] = v1.x; aT[(eb + 5) * 40 + r] = v1.y;
            aT[(eb + 6) * 40 + r] = v1.z; aT[(eb + 7) * 40 + r] = v1.w;
        }
        __syncthreads();
        const float* wp = ws + WEHT_OFF + (size_t)e0 * 256 + t;
#pragma unroll 4
        for (int e = 0; e < 64; e++) {
            float wv = wp[(size_t)e * 256];
            const float4* arow = (const float4*)&aT[e * 40];
#pragma unroll
            for (int j = 0; j < 8; j++) {
                float4 a4 = arow[j];
                acc[j * 4 + 0] = fmaf(a4.x, wv, acc[j * 4 + 0]);
                acc[j * 4 + 1] = fmaf(a4.y, wv, acc[j * 4 + 1]);
                acc[j * 4 + 2] = fmaf(a4.z, wv, acc[j * 4 + 2]);
                acc[j * 4 + 3] = fmaf(a4.w, wv, acc[j * 4 + 3]);
            }
        }
        __syncthreads();
    }
    float bcv = ws[BC_OFF + t];
#pragma unroll
    for (int r = 0; r < 32; r++)
        outp[(size_t)(R0 + r) * 256 + t] = acc[r] + bcv;
}

// ---------------- kernel 2: sequential scan, 1024 threads, 2 barriers/step --
// 128 blocks x 1024 threads; block b = batch elem b (1 block/CU, 4 waves/SIMD,
// hardware VGPR cap = 128). Per-thread weight state sized to FIT 128 regs:
//   whh: 16 float4 = 64 VGPR (e-range 16/wave), wsh: 8 float4 = 32 VGPR (j-range 8)
//   whs: LDS whs_l[e][s] 64 KB; wsu: LDS packed 32 KB.
// Thread (w = t>>6 in [0,16), lane):
//   phase A: cols h=lane*4..+3, e in [w*16,+16), j in [w*8,+8)
//   stack rows w*4..w*4+3 in registers sv[4]; halo via bnd[].
//   pv/uv computed by wave 0 alone after s1 (only row 0 consumes them).
//   hid reduce + ex prefetch on waves 4-7; phase-B act/gamma dots on waves 0-3.
__global__ __launch_bounds__(1024) void rnn_scan(
    const float* __restrict__ ws,
    const float* __restrict__ W_ha, const float* __restrict__ b_ha,
    const float* __restrict__ W_hg, const float* __restrict__ b_hg,
    const float* __restrict__ b_hs, const float* __restrict__ b_su,
    const float* __restrict__ empty_elem,
    float* __restrict__ out)
{
    __shared__ __align__(16) float hid[256];
    __shared__ __align__(16) float tops[128];
    __shared__ __align__(16) float partial[16 * 256]; // 16 KB
    __shared__ __align__(16) float ppb[16 * 64];      // 4 KB
    __shared__ __align__(16) float pub[16 * 64];      // 4 KB
    __shared__ __align__(16) float bnd[32 * 64];      // 8 KB old boundary rows
    __shared__ __align__(16) float wsu_l[8192];       // 32 KB, packed [j>>2][s][j&3]
    __shared__ __align__(16) float whs_l[16384];      // 64 KB, [e][s]
    __shared__ __align__(16) float whaL[1024];        // rows 0-2: W_ha, row 3: W_hg
    __shared__ float scal[4];

    const int t = threadIdx.x, lane = t & 63, w = t >> 6;
    const int b = blockIdx.x;

    // ---- weight registers (96 VGPRs total; loaded once, use sites unrolled)
    float4 whh[16], wsh[8];
    {
        const float* base = ws + WHHT_OFF + (size_t)(w * 16) * 256 + lane * 4;
#pragma unroll
        for (int e = 0; e < 16; e++) whh[e] = *(const float4*)(base + (size_t)e * 256);
        const float* base2 = ws + WSHT_OFF + (size_t)(w * 8) * 256 + lane * 4;
#pragma unroll
        for (int j = 0; j < 8; j++) wsh[j] = *(const float4*)(base2 + (size_t)j * 256);
    }
    // per-role bias registers
    float bscal = 0.f;
    if (lane == 0 && w < 4) bscal = (w < 3) ? b_ha[w] : b_hg[0];
    float bhs_r = 0.f, bsu_r = 0.f;
    if (w == 0) { bhs_r = b_hs[lane]; bsu_r = b_su[lane]; }

    // ---- init state: stack rows in registers, weights + small state in LDS
    const float ev = empty_elem[lane];
    float sv[4];
#pragma unroll
    for (int k = 0; k < 4; k++) sv[k] = ev;
    if (t < 256) hid[t] = 0.f;
    if (t < 128) tops[t] = empty_elem[t & 63];
    bnd[(w * 2) * 64 + lane] = ev;
    bnd[(w * 2 + 1) * 64 + lane] = ev;
    for (int i = t; i < 16384; i += 1024) whs_l[i] = ws[WHST_OFF + i]; // [e][s]
    for (int i = t; i < 8192; i += 1024) {
        int j = i >> 6, s = i & 63;
        wsu_l[(j >> 2) * 256 + s * 4 + (j & 3)] = ws[WSUT_OFF + i];
    }
    if (t < 1024) {
        int i = t;
        whaL[i] = (i < 768) ? W_ha[i] : W_hg[i - 768];
    }
    __syncthreads();

    // ex double-buffer: preload step 0 (waves 4-7 own hid elem h = t-256)
    float exv = (w >= 4 && w < 8) ? out[(size_t)b * 256 + (t - 256)] : 0.f;

    const float* whsp = &whs_l[(w * 16) * 64 + lane];  // + e*64 per element

    for (int ts = 0; ts < T_STEPS; ts++) {
        // prefetch NEXT step's ex BEFORE any store to out this step
        float exn = 0.f;
        if (w >= 4 && w < 8 && ts + 1 < T_STEPS)
            exn = out[((size_t)(ts + 1) * BATCH + b) * 256 + (t - 256)];

        // halo reads: neighbors' OLD boundary rows (published last step)
        float halo_lo = (w == 0) ? 0.f : bnd[((w - 1) * 2 + 1) * 64 + lane]; // row w*4-1
        float halo_hi = (w == 15) ? 0.f : bnd[((w + 1) * 2) * 64 + lane];    // row w*4+4

        // ======== phase A: all dot-product partials from old state
        float4 acc = make_float4(0.f, 0.f, 0.f, 0.f);
        float accP = 0.f, accU = 0.f;
#pragma unroll
        for (int eb = 0; eb < 4; eb++) {
            float4 hv = *(const float4*)&hid[w * 16 + eb * 4];
            acc.x = fmaf(whh[eb*4+0].x, hv.x, acc.x); acc.y = fmaf(whh[eb*4+0].y, hv.x, acc.y);
            acc.z = fmaf(whh[eb*4+0].z, hv.x, acc.z); acc.w = fmaf(whh[eb*4+0].w, hv.x, acc.w);
            acc.x = fmaf(whh[eb*4+1].x, hv.y, acc.x); acc.y = fmaf(whh[eb*4+1].y, hv.y, acc.y);
            acc.z = fmaf(whh[eb*4+1].z, hv.y, acc.z); acc.w = fmaf(whh[eb*4+1].w, hv.y, acc.w);
            acc.x = fmaf(whh[eb*4+2].x, hv.z, acc.x); acc.y = fmaf(whh[eb*4+2].y, hv.z, acc.y);
            acc.z = fmaf(whh[eb*4+2].z, hv.z, acc.z); acc.w = fmaf(whh[eb*4+2].w, hv.z, acc.w);
            acc.x = fmaf(whh[eb*4+3].x, hv.w, acc.x); acc.y = fmaf(whh[eb*4+3].y, hv.w, acc.y);
            acc.z = fmaf(whh[eb*4+3].z, hv.w, acc.z); acc.w = fmaf(whh[eb*4+3].w, hv.w, acc.w);
            accP = fmaf(whsp[(eb*4+0)*64], hv.x, accP);
            accP = fmaf(whsp[(eb*4+1)*64], hv.y, accP);
            accP = fmaf(whsp[(eb*4+2)*64], hv.z, accP);
            accP = fmaf(whsp[(eb*4+3)*64], hv.w, accP);
        }
#pragma unroll
        for (int jb = 0; jb < 2; jb++) {
            float4 tv = *(const float4*)&tops[w * 8 + jb * 4];
            acc.x = fmaf(wsh[jb*4+0].x, tv.x, acc.x); acc.y = fmaf(wsh[jb*4+0].y, tv.x, acc.y);
            acc.z = fmaf(wsh[jb*4+0].z, tv.x, acc.z); acc.w = fmaf(wsh[jb*4+0].w, tv.x, acc.w);
            acc.x = fmaf(wsh[jb*4+1].x, tv.y, acc.x); acc.y = fmaf(wsh[jb*4+1].y, tv.y, acc.y);
            acc.z = fmaf(wsh[jb*4+1].z, tv.y, acc.z); acc.w = fmaf(wsh[jb*4+1].w, tv.y, acc.w);
            acc.x = fmaf(wsh[jb*4+2].x, tv.z, acc.x); acc.y = fmaf(wsh[jb*4+2].y, tv.z, acc.y);
            acc.z = fmaf(wsh[jb*4+2].z, tv.z, acc.z); acc.w = fmaf(wsh[jb*4+2].w, tv.z, acc.w);
            acc.x = fmaf(wsh[jb*4+3].x, tv.w, acc.x); acc.y = fmaf(wsh[jb*4+3].y, tv.w, acc.y);
            acc.z = fmaf(wsh[jb*4+3].z, tv.w, acc.z); acc.w = fmaf(wsh[jb*4+3].w, tv.w, acc.w);
            float4 su = *(const float4*)&wsu_l[(w * 2 + jb) * 256 + lane * 4];
            accU = fmaf(su.x, tv.x, accU);
            accU = fmaf(su.y, tv.y, accU);
            accU = fmaf(su.z, tv.z, accU);
            accU = fmaf(su.w, tv.w, accU);
        }
        *(float4*)&partial[w * 256 + lane * 4] = acc;
        ppb[w * 64 + lane] = accP;
        pub[w * 64 + lane] = accU;

        // ======== phase B: act logits + gamma dots (waves 0..3, old hid)
        if (w < 4) {
            float bd = 0.f;
#pragma unroll
            for (int k = 0; k < 4; k++)
                bd = fmaf(whaL[w * 256 + k * 64 + lane], hid[k * 64 + lane], bd);
#pragma unroll
            for (int off = 32; off > 0; off >>= 1) bd += __shfl_down(bd, off);
            if (lane == 0) scal[w] = bd + bscal;
        }
        __syncthreads(); // s1: partials + ppb/pub + scal visible; all old-state reads done

        // ---- wave 0 alone: push/pop values (only consumed by stack row 0)
        float pvv = 0.f, uvv = 0.f;
        if (w == 0) {
            float v1 = bhs_r, v2 = bsu_r;
#pragma unroll
            for (int q = 0; q < 16; q++) v1 += ppb[q * 64 + lane];
#pragma unroll
            for (int q = 0; q < 16; q++) v2 += pub[q * 64 + lane];
            pvv = fmaxf(v1, 0.f);
            uvv = fmaxf(v2, 0.f);
        }

        // ---- hid reduce (waves 4..7 own one h each)
        if (w >= 4 && w < 8) {
            int h = t - 256;
            float mh = exv;
#pragma unroll
            for (int q = 0; q < 16; q++) mh += partial[q * 256 + h];
            float nh = fmaxf(mh, 0.f);
            hid[h] = nh;
            out[((size_t)ts * BATCH + b) * 256 + h] = nh;
        }

        // ---- softmax -> sharpen (all threads, wave-uniform scal broadcast)
        float l0 = scal[0], l1 = scal[1], l2 = scal[2], gv = scal[3];
        float g = 1.f + ((gv > 15.f) ? gv : log1pf(expf(gv)));
        float m = fmaxf(l0, fmaxf(l1, l2));
        float z = expf(l0 - m) + expf(l1 - m) + expf(l2 - m);
        float lz = logf(z);
        float s0  = expf(g * (l0 - m - lz));
        float s1v = expf(g * (l1 - m - lz));
        float s2v = expf(g * (l2 - m - lz));
        float S = s0 + s1v + s2v + 1e-16f;
        float p0 = s0 / S, p1 = s1v / S, p2 = s2v / S;

        if (t == 0) {
            int am = 0; float bm = s0;
            if (s1v > bm) { bm = s1v; am = 1; }
            if (s2v > bm) { bm = s2v; am = 2; }
            out[ACTS_OFF + ts * BATCH + b] = (float)am;
        }

        // ---- stack blend fully in registers (rows w*4 .. w*4+3)
        {
            float nv[4];
            float below0 = (w == 0) ? pvv : halo_lo;     // push src for row w*4
            float pop0   = (w == 0) ? uvv : sv[1];       // pop src (row 0 gets u_val)
            nv[0] = fmaf(p0, below0, fmaf(p1, pop0, p2 * sv[0]));
            nv[1] = fmaf(p0, sv[0], fmaf(p1, sv[2], p2 * sv[1]));
            nv[2] = fmaf(p0, sv[1], fmaf(p1, sv[3], p2 * sv[2]));
            nv[3] = fmaf(p0, sv[2], fmaf(p1, halo_hi, p2 * sv[3]));
#pragma unroll
            for (int k = 0; k < 4; k++) sv[k] = nv[k];
        }
        // publish new boundary rows (next step's "old" halo) + tops
        bnd[(w * 2) * 64 + lane] = sv[0];
        bnd[(w * 2 + 1) * 64 + lane] = sv[3];
        if (w == 0) { tops[lane] = sv[0]; tops[64 + lane] = sv[1]; }

        exv = exn;
        __syncthreads(); // s2: new hid/tops/bnd visible for next step
    }

    // ---- final hid & stack
    if (t < 256) out[HID_OFF + (size_t)b * 256 + t] = hid[t];
#pragma unroll
    for (int k = 0; k < 4; k++)
        out[STACK_OFF + (size_t)b * 4096 + (w * 4 + k) * 64 + lane] = sv[k];
}

// ---------------- launcher ---------------------------------------------------
extern "C" void kernel_launch(void* const* d_in, const int* in_sizes, int n_in,
                              void* d_out, int out_size, void* d_ws, size_t ws_size,
                              hipStream_t stream)
{
    (void)in_sizes; (void)n_in; (void)out_size; (void)ws_size;
    const int*   inputs     = (const int*)d_in[0];
    const float* emb_W      = (const float*)d_in[1];
    const float* W_hh       = (const float*)d_in[2];
    const float* b_hh       = (const float*)d_in[3];
    const float* W_eh       = (const float*)d_in[4];
    const float* b_eh       = (const float*)d_in[5];
    const float* W_ha       = (const float*)d_in[6];
    const float* b_ha       = (const float*)d_in[7];
    const float* W_hg       = (const float*)d_in[8];
    const float* b_hg       = (const float*)d_in[9];
    const float* W_hs       = (const float*)d_in[10];
    const float* b_hs       = (const float*)d_in[11];
    const float* W_sh       = (const float*)d_in[12];
    const float* b_sh       = (const float*)d_in[13];
    const float* W_su       = (const float*)d_in[14];
    const float* b_su       = (const float*)d_in[15];
    const float* empty_elem = (const float*)d_in[16];
    float* out = (float*)d_out;
    float* ws  = (float*)d_ws;

    hipLaunchKernelGGL(prep_kernel, dim3(737), dim3(256), 0, stream,
                       W_hh, b_hh, W_eh, b_eh, W_sh, b_sh, W_hs, W_su, ws);
    hipLaunchKernelGGL(ex_gemm, dim3(1024), dim3(256), 0, stream,
                       inputs, emb_W, ws, out);
    hipLaunchKernelGGL(rnn_scan, dim3(128), dim3(1024), 0, stream,
                       ws, W_ha, b_ha, W_hg, b_hg, b_hs, b_su, empty_elem, out);
}

// Round 4
// 802.452 us; speedup vs baseline: 1.6339x; 1.6339x over previous
//
#include <hip/hip_runtime.h>

// EncoderSRNN: T=256 steps, B=128, HDIM=EDIM=256, SSZ=64, SDIM=64, SDEPTH=2, NACT=3
#define T_STEPS 256
#define BATCH 128

// ws float offsets (transposed weights + combined bias)
#define WEHT_OFF 0         // [e][h] 256x256
#define WHHT_OFF 65536     // [e][h] 256x256
#define WSHT_OFF 131072    // [j][h] 128x256
#define WHST_OFF 163840    // [e][s] 256x64
#define WSUT_OFF 180224    // [j][s] 128x64
#define BC_OFF   188416    // bc[h] = b_eh+b_hh+b_sh

#define HID_OFF   8388608
#define STACK_OFF 8421376
#define ACTS_OFF  8945664

// ---------------- kernel 0: transpose weights into ws, fold biases ----------
__global__ __launch_bounds__(256) void prep_kernel(
    const float* __restrict__ W_hh, const float* __restrict__ b_hh,
    const float* __restrict__ W_eh, const float* __restrict__ b_eh,
    const float* __restrict__ W_sh, const float* __restrict__ b_sh,
    const float* __restrict__ W_hs, const float* __restrict__ W_su,
    float* __restrict__ ws)
{
    int idx = blockIdx.x * 256 + threadIdx.x;
    if (idx < 65536) {                       // W_ehT[e][h] = W_eh[h][e]
        ws[WEHT_OFF + idx] = W_eh[(idx & 255) * 256 + (idx >> 8)];
    } else if (idx < 131072) {               // W_hhT
        int k = idx - 65536;
        ws[WHHT_OFF + k] = W_hh[(k & 255) * 256 + (k >> 8)];
    } else if (idx < 163840) {               // W_shT[j][h] = W_sh[h][j]
        int k = idx - 131072;
        ws[WSHT_OFF + k] = W_sh[(k & 255) * 128 + (k >> 8)];
    } else if (idx < 180224) {               // W_hsT[e][s] = W_hs[s][e]
        int k = idx - 163840;
        ws[WHST_OFF + k] = W_hs[(k & 63) * 256 + (k >> 6)];
    } else if (idx < 188416) {               // W_suT[j][s] = W_su[s][j]
        int k = idx - 180224;
        ws[WSUT_OFF + k] = W_su[(k & 63) * 128 + (k >> 6)];
    } else if (idx < 188672) {
        int k = idx - 188416;
        ws[BC_OFF + k] = b_eh[k] + b_hh[k] + b_sh[k];
    }
}

// ---------------- kernel 1: ex[t,b,h] = emb_W[tok]@W_eh.T + bc  -------------
__global__ __launch_bounds__(256) void ex_gemm(
    const int* __restrict__ tokens, const float* __restrict__ emb_W,
    const float* __restrict__ ws, float* __restrict__ outp)
{
    __shared__ __align__(16) float aT[64 * 40];
    __shared__ int tok[32];
    const int t = threadIdx.x;
    const int R0 = blockIdx.x * 32;
    if (t < 32) tok[t] = tokens[R0 + t];
    __syncthreads();

    float acc[32];
#pragma unroll
    for (int r = 0; r < 32; r++) acc[r] = 0.f;

    for (int e0 = 0; e0 < 256; e0 += 64) {
        {
            int r = t >> 3, seg = t & 7;
            const float* src = emb_W + (size_t)tok[r] * 256 + e0 + seg * 8;
            float4 v0 = *(const float4*)(src);
            float4 v1 = *(const float4*)(src + 4);
            int eb = seg * 8;
            aT[(eb + 0) * 40 + r] = v0.x; aT[(eb + 1) * 40 + r] = v0.y;
            aT[(eb + 2) * 40 + r] = v0.z; aT[(eb + 3) * 40 + r] = v0.w;
            aT[(eb + 4) * 40 + r] = v1.x; aT[(eb + 5) * 40 + r] = v1.y;
            aT[(eb + 6) * 40 + r] = v1.z; aT[(eb + 7) * 40 + r] = v1.w;
        }
        __syncthreads();
        const float* wp = ws + WEHT_OFF + (size_t)e0 * 256 + t;
#pragma unroll 4
        for (int e = 0; e < 64; e++) {
            float wv = wp[(size_t)e * 256];
            const float4* arow = (const float4*)&aT[e * 40];
#pragma unroll
            for (int j = 0; j < 8; j++) {
                float4 a4 = arow[j];
                acc[j * 4 + 0] = fmaf(a4.x, wv, acc[j * 4 + 0]);
                acc[j * 4 + 1] = fmaf(a4.y, wv, acc[j * 4 + 1]);
                acc[j * 4 + 2] = fmaf(a4.z, wv, acc[j * 4 + 2]);
                acc[j * 4 + 3] = fmaf(a4.w, wv, acc[j * 4 + 3]);
            }
        }
        __syncthreads();
    }
    float bcv = ws[BC_OFF + t];
#pragma unroll
    for (int r = 0; r < 32; r++)
        outp[(size_t)(R0 + r) * 256 + t] = acc[r] + bcv;
}

// ---------------- kernel 2: sequential scan, 2 barriers/step ----------------
// 128 blocks x 512 threads; block b = batch elem b (1 block/CU due to 120KB LDS,
// so 2 waves/SIMD -> VGPR budget 256). Weight registers are passed through an
// empty asm(+v) once after load: values become non-rematerializable, forcing the
// allocator to keep them LIVE in VGPRs instead of re-issuing the L2 loads every
// step (rounds 0-2 all showed VGPR_Count=128 with per-step weight reloads).
//   whh: 32 float4 = 128 VGPR, wsh: 16 float4 = 64 VGPR (192 pinned)
//   whs: LDS whs_l[e][s] 64 KB; wsu: LDS packed 32 KB.
__attribute__((amdgpu_flat_work_group_size(512, 512)))
__attribute__((amdgpu_waves_per_eu(2, 2)))
__global__ void rnn_scan(
    const float* __restrict__ ws,
    const float* __restrict__ W_ha, const float* __restrict__ b_ha,
    const float* __restrict__ W_hg, const float* __restrict__ b_hg,
    const float* __restrict__ b_hs, const float* __restrict__ b_su,
    const float* __restrict__ empty_elem,
    float* __restrict__ out)
{
    __shared__ __align__(16) float hid[256];
    __shared__ __align__(16) float tops[128];
    __shared__ __align__(16) float partial[8 * 256]; // 8 KB
    __shared__ __align__(16) float ppb[8 * 64];
    __shared__ __align__(16) float pub[8 * 64];
    __shared__ __align__(16) float bnd[16 * 64];     // old boundary rows
    __shared__ __align__(16) float wsu_l[8192];      // 32 KB, packed [j>>2][s][j&3]
    __shared__ __align__(16) float whs_l[16384];     // 64 KB, [e][s] (lane-contiguous)
    __shared__ __align__(16) float whaL[1024];       // rows 0-2: W_ha, row 3: W_hg
    __shared__ float scal[4];

    const int t = threadIdx.x, lane = t & 63, w = t >> 6;
    const int b = blockIdx.x;

    // ---- weight registers (loaded once, then liveness-pinned)
    float4 whh[32], wsh[16];
    {
        const float* base = ws + WHHT_OFF + (size_t)(w * 32) * 256 + lane * 4;
#pragma unroll
        for (int e = 0; e < 32; e++) whh[e] = *(const float4*)(base + (size_t)e * 256);
        const float* base2 = ws + WSHT_OFF + (size_t)(w * 16) * 256 + lane * 4;
#pragma unroll
        for (int j = 0; j < 16; j++) wsh[j] = *(const float4*)(base2 + (size_t)j * 256);
    }
    // pin: empty asm makes each value an opaque def -> not rematerializable,
    // so the register allocator must keep all 192 weight VGPRs live.
#pragma unroll
    for (int e = 0; e < 32; e++)
        asm volatile("" : "+v"(whh[e].x), "+v"(whh[e].y), "+v"(whh[e].z), "+v"(whh[e].w));
#pragma unroll
    for (int j = 0; j < 16; j++)
        asm volatile("" : "+v"(wsh[j].x), "+v"(wsh[j].y), "+v"(wsh[j].z), "+v"(wsh[j].w));

    // per-role bias registers
    float bscal = 0.f;
    if (lane == 0 && w < 4) bscal = (w < 3) ? b_ha[w] : b_hg[0];
    float bhs_r = 0.f, bsu_r = 0.f;
    if (w == 0) { bhs_r = b_hs[lane]; bsu_r = b_su[lane]; }

    // ---- init state: stack rows in registers, weights + small state in LDS
    const float ev = empty_elem[lane];
    float sv[8];
#pragma unroll
    for (int k = 0; k < 8; k++) sv[k] = ev;
    if (t < 256) hid[t] = 0.f;
    if (t < 128) tops[t] = empty_elem[t & 63];
    bnd[(w * 2) * 64 + lane] = ev;
    bnd[(w * 2 + 1) * 64 + lane] = ev;
    for (int i = t; i < 16384; i += 512) whs_l[i] = ws[WHST_OFF + i]; // [e][s]
    for (int i = t; i < 8192; i += 512) {
        int j = i >> 6, s = i & 63;
        wsu_l[(j >> 2) * 256 + s * 4 + (j & 3)] = ws[WSUT_OFF + i];
    }
    for (int i = t; i < 1024; i += 512)
        whaL[i] = (i < 768) ? W_ha[i] : W_hg[i - 768];
    __syncthreads();

    // ex double-buffer: preload step 0 (waves 4-7 own hid elem h = t-256)
    float exv = (w >= 4) ? out[(size_t)b * 256 + (t - 256)] : 0.f;

    const float* whsp = &whs_l[(w * 32) * 64 + lane];  // + e*64 per element

    for (int ts = 0; ts < T_STEPS; ts++) {
        // prefetch NEXT step's ex BEFORE any store to out this step
        float exn = 0.f;
        if (w >= 4 && ts + 1 < T_STEPS)
            exn = out[((size_t)(ts + 1) * BATCH + b) * 256 + (t - 256)];

        // halo reads: neighbors' OLD boundary rows (published last step)
        float halo_lo = (w == 0) ? 0.f : bnd[((w - 1) * 2 + 1) * 64 + lane]; // row w*8-1
        float halo_hi = (w == 7) ? 0.f : bnd[((w + 1) * 2) * 64 + lane];     // row w*8+8

        // ======== phase A: all dot-product partials from old state
        float4 acc = make_float4(0.f, 0.f, 0.f, 0.f);
        float accP = 0.f, accU = 0.f;
#pragma unroll
        for (int eb = 0; eb < 8; eb++) {
            float4 hv = *(const float4*)&hid[w * 32 + eb * 4];
            acc.x = fmaf(whh[eb*4+0].x, hv.x, acc.x); acc.y = fmaf(whh[eb*4+0].y, hv.x, acc.y);
            acc.z = fmaf(whh[eb*4+0].z, hv.x, acc.z); acc.w = fmaf(whh[eb*4+0].w, hv.x, acc.w);
            acc.x = fmaf(whh[eb*4+1].x, hv.y, acc.x); acc.y = fmaf(whh[eb*4+1].y, hv.y, acc.y);
            acc.z = fmaf(whh[eb*4+1].z, hv.y, acc.z); acc.w = fmaf(whh[eb*4+1].w, hv.y, acc.w);
            acc.x = fmaf(whh[eb*4+2].x, hv.z, acc.x); acc.y = fmaf(whh[eb*4+2].y, hv.z, acc.y);
            acc.z = fmaf(whh[eb*4+2].z, hv.z, acc.z); acc.w = fmaf(whh[eb*4+2].w, hv.z, acc.w);
            acc.x = fmaf(whh[eb*4+3].x, hv.w, acc.x); acc.y = fmaf(whh[eb*4+3].y, hv.w, acc.y);
            acc.z = fmaf(whh[eb*4+3].z, hv.w, acc.z); acc.w = fmaf(whh[eb*4+3].w, hv.w, acc.w);
            accP = fmaf(whsp[(eb*4+0)*64], hv.x, accP);
            accP = fmaf(whsp[(eb*4+1)*64], hv.y, accP);
            accP = fmaf(whsp[(eb*4+2)*64], hv.z, accP);
            accP = fmaf(whsp[(eb*4+3)*64], hv.w, accP);
        }
#pragma unroll
        for (int jb = 0; jb < 4; jb++) {
            float4 tv = *(const float4*)&tops[w * 16 + jb * 4];
            acc.x = fmaf(wsh[jb*4+0].x, tv.x, acc.x); acc.y = fmaf(wsh[jb*4+0].y, tv.x, acc.y);
            acc.z = fmaf(wsh[jb*4+0].z, tv.x, acc.z); acc.w = fmaf(wsh[jb*4+0].w, tv.x, acc.w);
            acc.x = fmaf(wsh[jb*4+1].x, tv.y, acc.x); acc.y = fmaf(wsh[jb*4+1].y, tv.y, acc.y);
            acc.z = fmaf(wsh[jb*4+1].z, tv.y, acc.z); acc.w = fmaf(wsh[jb*4+1].w, tv.y, acc.w);
            acc.x = fmaf(wsh[jb*4+2].x, tv.z, acc.x); acc.y = fmaf(wsh[jb*4+2].y, tv.z, acc.y);
            acc.z = fmaf(wsh[jb*4+2].z, tv.z, acc.z); acc.w = fmaf(wsh[jb*4+2].w, tv.z, acc.w);
            acc.x = fmaf(wsh[jb*4+3].x, tv.w, acc.x); acc.y = fmaf(wsh[jb*4+3].y, tv.w, acc.y);
            acc.z = fmaf(wsh[jb*4+3].z, tv.w, acc.z); acc.w = fmaf(wsh[jb*4+3].w, tv.w, acc.w);
            float4 su = *(const float4*)&wsu_l[(w * 4 + jb) * 256 + lane * 4];
            accU = fmaf(su.x, tv.x, accU);
            accU = fmaf(su.y, tv.y, accU);
            accU = fmaf(su.z, tv.z, accU);
            accU = fmaf(su.w, tv.w, accU);
        }
        *(float4*)&partial[w * 256 + lane * 4] = acc;
        ppb[w * 64 + lane] = accP;
        pub[w * 64 + lane] = accU;

        // ======== phase B: act logits + gamma dots (waves 0..3, old hid)
        if (w < 4) {
            float bd = 0.f;
#pragma unroll
            for (int k = 0; k < 4; k++)
                bd = fmaf(whaL[w * 256 + k * 64 + lane], hid[k * 64 + lane], bd);
#pragma unroll
            for (int off = 32; off > 0; off >>= 1) bd += __shfl_down(bd, off);
            if (lane == 0) scal[w] = bd + bscal;
        }
        __syncthreads(); // s1: partials + ppb/pub + scal visible; all old-state reads done

        // ---- wave 0 alone: push/pop values (only consumed by stack row 0)
        float pvv = 0.f, uvv = 0.f;
        if (w == 0) {
            float v1 = bhs_r, v2 = bsu_r;
#pragma unroll
            for (int q = 0; q < 8; q++) v1 += ppb[q * 64 + lane];
#pragma unroll
            for (int q = 0; q < 8; q++) v2 += pub[q * 64 + lane];
            pvv = fmaxf(v1, 0.f);
            uvv = fmaxf(v2, 0.f);
        }

        // ---- hid reduce (waves 4..7 own one h each)
        if (w >= 4) {
            int h = t - 256;
            float mh = exv;
#pragma unroll
            for (int q = 0; q < 8; q++) mh += partial[q * 256 + h];
            float nh = fmaxf(mh, 0.f);
            hid[h] = nh;
            out[((size_t)ts * BATCH + b) * 256 + h] = nh;
        }

        // ---- softmax -> sharpen (all threads, wave-uniform scal broadcast)
        float l0 = scal[0], l1 = scal[1], l2 = scal[2], gv = scal[3];
        float g = 1.f + ((gv > 15.f) ? gv : log1pf(expf(gv)));
        float m = fmaxf(l0, fmaxf(l1, l2));
        float z = expf(l0 - m) + expf(l1 - m) + expf(l2 - m);
        float lz = logf(z);
        float s0  = expf(g * (l0 - m - lz));
        float s1v = expf(g * (l1 - m - lz));
        float s2v = expf(g * (l2 - m - lz));
        float S = s0 + s1v + s2v + 1e-16f;
        float p0 = s0 / S, p1 = s1v / S, p2 = s2v / S;

        if (t == 0) {
            int am = 0; float bm = s0;
            if (s1v > bm) { bm = s1v; am = 1; }
            if (s2v > bm) { bm = s2v; am = 2; }
            out[ACTS_OFF + ts * BATCH + b] = (float)am;
        }

        // ---- stack blend fully in registers
        {
            float nv[8];
            float below0 = (w == 0) ? pvv : halo_lo;     // push src for row w*8
            float pop0   = (w == 0) ? uvv : sv[1];       // pop src (row 0 gets u_val)
            nv[0] = fmaf(p0, below0, fmaf(p1, pop0, p2 * sv[0]));
#pragma unroll
            for (int k = 1; k < 7; k++)
                nv[k] = fmaf(p0, sv[k - 1], fmaf(p1, sv[k + 1], p2 * sv[k]));
            nv[7] = fmaf(p0, sv[6], fmaf(p1, halo_hi, p2 * sv[7]));
#pragma unroll
            for (int k = 0; k < 8; k++) sv[k] = nv[k];
        }
        // publish new boundary rows (next step's "old" halo) + tops
        bnd[(w * 2) * 64 + lane] = sv[0];
        bnd[(w * 2 + 1) * 64 + lane] = sv[7];
        if (w == 0) { tops[lane] = sv[0]; tops[64 + lane] = sv[1]; }

        exv = exn;
        __syncthreads(); // s2: new hid/tops/bnd visible for next step
    }

    // ---- final hid & stack
    if (t < 256) out[HID_OFF + (size_t)b * 256 + t] = hid[t];
#pragma unroll
    for (int k = 0; k < 8; k++)
        out[STACK_OFF + (size_t)b * 4096 + (w * 8 + k) * 64 + lane] = sv[k];
}

// ---------------- launcher ---------------------------------------------------
extern "C" void kernel_launch(void* const* d_in, const int* in_sizes, int n_in,
                              void* d_out, int out_size, void* d_ws, size_t ws_size,
                              hipStream_t stream)
{
    (void)in_sizes; (void)n_in; (void)out_size; (void)ws_size;
    const int*   inputs     = (const int*)d_in[0];
    const float* emb_W      = (const float*)d_in[1];
    const float* W_hh       = (const float*)d_in[2];
    const float* b_hh       = (const float*)d_in[3];
    const float* W_eh       = (const float*)d_in[4];
    const float* b_eh       = (const float*)d_in[5];
    const float* W_ha       = (const float*)d_in[6];
    const float* b_ha       = (const float*)d_in[7];
    const float* W_hg       = (const float*)d_in[8];
    const float* b_hg       = (const float*)d_in[9];
    const float* W_hs       = (const float*)d_in[10];
    const float* b_hs       = (const float*)d_in[11];
    const float* W_sh       = (const float*)d_in[12];
    const float* b_sh       = (const float*)d_in[13];
    const float* W_su       = (const float*)d_in[14];
    const float* b_su       = (const float*)d_in[15];
    const float* empty_elem = (const float*)d_in[16];
    float* out = (float*)d_out;
    float* ws  = (float*)d_ws;

    hipLaunchKernelGGL(prep_kernel, dim3(737), dim3(256), 0, stream,
                       W_hh, b_hh, W_eh, b_eh, W_sh, b_sh, W_hs, W_su, ws);
    hipLaunchKernelGGL(ex_gemm, dim3(1024), dim3(256), 0, stream,
                       inputs, emb_W, ws, out);
    hipLaunchKernelGGL(rnn_scan, dim3(128), dim3(512), 0, stream,
                       ws, W_ha, b_ha, W_hg, b_hg, b_hs, b_su, empty_elem, out);
}

// Round 5
// 689.116 us; speedup vs baseline: 1.9026x; 1.1645x over previous
//
#include <hip/hip_runtime.h>

// EncoderSRNN: T=256 steps, B=128, HDIM=EDIM=256, SSZ=64, SDIM=64, SDEPTH=2, NACT=3
#define T_STEPS 256
#define BATCH 128

// ws float offsets (transposed weights + combined bias)
#define WEHT_OFF 0         // [e][h] 256x256
#define WHHT_OFF 65536     // [e][h] 256x256
#define WSHT_OFF 131072    // [j][h] 128x256
#define WHST_OFF 163840    // [e][s] 256x64
#define WSUT_OFF 180224    // [j][s] 128x64
#define BC_OFF   188416    // bc[h] = b_eh+b_hh+b_sh

#define HID_OFF   8388608
#define STACK_OFF 8421376
#define ACTS_OFF  8945664

// In-loop barrier: LDS-only fence + raw barrier. Deliberately NO vmcnt drain:
// __syncthreads() would emit s_waitcnt vmcnt(0) lgkmcnt(0), forcing every step
// to wait for the exn HBM prefetch (at s1) and the nh store ack (at s2).
// All cross-wave handoffs are DS ops (lgkmcnt); all global ops in the loop are
// same-thread ordered (exn load / nh store to the same address are program-order
// within one thread), so vmcnt ordering at the barrier is unnecessary.
#define BAR_LDS() do { \
    asm volatile("s_waitcnt lgkmcnt(0)" ::: "memory"); \
    __builtin_amdgcn_s_barrier(); \
} while (0)

// ---------------- kernel 0: transpose weights into ws, fold biases ----------
__global__ __launch_bounds__(256) void prep_kernel(
    const float* __restrict__ W_hh, const float* __restrict__ b_hh,
    const float* __restrict__ W_eh, const float* __restrict__ b_eh,
    const float* __restrict__ W_sh, const float* __restrict__ b_sh,
    const float* __restrict__ W_hs, const float* __restrict__ W_su,
    float* __restrict__ ws)
{
    int idx = blockIdx.x * 256 + threadIdx.x;
    if (idx < 65536) {                       // W_ehT[e][h] = W_eh[h][e]
        ws[WEHT_OFF + idx] = W_eh[(idx & 255) * 256 + (idx >> 8)];
    } else if (idx < 131072) {               // W_hhT
        int k = idx - 65536;
        ws[WHHT_OFF + k] = W_hh[(k & 255) * 256 + (k >> 8)];
    } else if (idx < 163840) {               // W_shT[j][h] = W_sh[h][j]
        int k = idx - 131072;
        ws[WSHT_OFF + k] = W_sh[(k & 255) * 128 + (k >> 8)];
    } else if (idx < 180224) {               // W_hsT[e][s] = W_hs[s][e]
        int k = idx - 163840;
        ws[WHST_OFF + k] = W_hs[(k & 63) * 256 + (k >> 6)];
    } else if (idx < 188416) {               // W_suT[j][s] = W_su[s][j]
        int k = idx - 180224;
        ws[WSUT_OFF + k] = W_su[(k & 63) * 128 + (k >> 6)];
    } else if (idx < 188672) {
        int k = idx - 188416;
        ws[BC_OFF + k] = b_eh[k] + b_hh[k] + b_sh[k];
    }
}

// ---------------- kernel 1: ex[t,b,h] = emb_W[tok]@W_eh.T + bc  -------------
__global__ __launch_bounds__(256) void ex_gemm(
    const int* __restrict__ tokens, const float* __restrict__ emb_W,
    const float* __restrict__ ws, float* __restrict__ outp)
{
    __shared__ __align__(16) float aT[64 * 40];
    __shared__ int tok[32];
    const int t = threadIdx.x;
    const int R0 = blockIdx.x * 32;
    if (t < 32) tok[t] = tokens[R0 + t];
    __syncthreads();

    float acc[32];
#pragma unroll
    for (int r = 0; r < 32; r++) acc[r] = 0.f;

    for (int e0 = 0; e0 < 256; e0 += 64) {
        {
            int r = t >> 3, seg = t & 7;
            const float* src = emb_W + (size_t)tok[r] * 256 + e0 + seg * 8;
            float4 v0 = *(const float4*)(src);
            float4 v1 = *(const float4*)(src + 4);
            int eb = seg * 8;
            aT[(eb + 0) * 40 + r] = v0.x; aT[(eb + 1) * 40 + r] = v0.y;
            aT[(eb + 2) * 40 + r] = v0.z; aT[(eb + 3) * 40 + r] = v0.w;
            aT[(eb + 4) * 40 + r] = v1.x; aT[(eb + 5) * 40 + r] = v1.y;
            aT[(eb + 6) * 40 + r] = v1.z; aT[(eb + 7) * 40 + r] = v1.w;
        }
        __syncthreads();
        const float* wp = ws + WEHT_OFF + (size_t)e0 * 256 + t;
#pragma unroll 4
        for (int e = 0; e < 64; e++) {
            float wv = wp[(size_t)e * 256];
            const float4* arow = (const float4*)&aT[e * 40];
#pragma unroll
            for (int j = 0; j < 8; j++) {
                float4 a4 = arow[j];
                acc[j * 4 + 0] = fmaf(a4.x, wv, acc[j * 4 + 0]);
                acc[j * 4 + 1] = fmaf(a4.y, wv, acc[j * 4 + 1]);
                acc[j * 4 + 2] = fmaf(a4.z, wv, acc[j * 4 + 2]);
                acc[j * 4 + 3] = fmaf(a4.w, wv, acc[j * 4 + 3]);
            }
        }
        __syncthreads();
    }
    float bcv = ws[BC_OFF + t];
#pragma unroll
    for (int r = 0; r < 32; r++)
        outp[(size_t)(R0 + r) * 256 + t] = acc[r] + bcv;
}

// ---------------- kernel 2: sequential scan, 2 LDS-only barriers/step -------
// 128 blocks x 512 threads; block b = batch elem b (1 block/CU due to 120KB LDS,
// so 2 waves/SIMD -> unified reg budget ~256/wave). Weight registers are passed
// through an empty asm(+v) once after load: values become non-rematerializable,
// forcing the allocator to keep them live on-chip (VGPR/AGPR) instead of
// re-issuing the L2 loads every step (proven r4: WRITE_SIZE -5.7MB, -22% time).
//   whh: 32 float4 = 128 regs, wsh: 16 float4 = 64 regs (192 pinned; do NOT pin
//   more - budget is ~256/wave and whs pinning would push into scratch spill)
//   whs: LDS whs_l[e][s] 64 KB; wsu: LDS packed 32 KB.
__attribute__((amdgpu_flat_work_group_size(512, 512)))
__attribute__((amdgpu_waves_per_eu(2, 2)))
__global__ void rnn_scan(
    const float* __restrict__ ws,
    const float* __restrict__ W_ha, const float* __restrict__ b_ha,
    const float* __restrict__ W_hg, const float* __restrict__ b_hg,
    const float* __restrict__ b_hs, const float* __restrict__ b_su,
    const float* __restrict__ empty_elem,
    float* __restrict__ out)
{
    __shared__ __align__(16) float hid[256];
    __shared__ __align__(16) float tops[128];
    __shared__ __align__(16) float partial[8 * 256]; // 8 KB
    __shared__ __align__(16) float ppb[8 * 64];
    __shared__ __align__(16) float pub[8 * 64];
    __shared__ __align__(16) float bnd[16 * 64];     // old boundary rows
    __shared__ __align__(16) float wsu_l[8192];      // 32 KB, packed [j>>2][s][j&3]
    __shared__ __align__(16) float whs_l[16384];     // 64 KB, [e][s] (lane-contiguous)
    __shared__ __align__(16) float whaL[1024];       // rows 0-2: W_ha, row 3: W_hg
    __shared__ float scal[4];

    const int t = threadIdx.x, lane = t & 63, w = t >> 6;
    const int b = blockIdx.x;

    // ---- weight registers (loaded once, then liveness-pinned)
    float4 whh[32], wsh[16];
    {
        const float* base = ws + WHHT_OFF + (size_t)(w * 32) * 256 + lane * 4;
#pragma unroll
        for (int e = 0; e < 32; e++) whh[e] = *(const float4*)(base + (size_t)e * 256);
        const float* base2 = ws + WSHT_OFF + (size_t)(w * 16) * 256 + lane * 4;
#pragma unroll
        for (int j = 0; j < 16; j++) wsh[j] = *(const float4*)(base2 + (size_t)j * 256);
    }
    // pin: empty asm makes each value an opaque def -> not rematerializable,
    // so the register allocator must keep all 192 weight regs live on-chip.
#pragma unroll
    for (int e = 0; e < 32; e++)
        asm volatile("" : "+v"(whh[e].x), "+v"(whh[e].y), "+v"(whh[e].z), "+v"(whh[e].w));
#pragma unroll
    for (int j = 0; j < 16; j++)
        asm volatile("" : "+v"(wsh[j].x), "+v"(wsh[j].y), "+v"(wsh[j].z), "+v"(wsh[j].w));

    // per-role bias registers
    float bscal = 0.f;
    if (lane == 0 && w < 4) bscal = (w < 3) ? b_ha[w] : b_hg[0];
    float bhs_r = 0.f, bsu_r = 0.f;
    if (w == 0) { bhs_r = b_hs[lane]; bsu_r = b_su[lane]; }

    // ---- init state: stack rows in registers, weights + small state in LDS
    const float ev = empty_elem[lane];
    float sv[8];
#pragma unroll
    for (int k = 0; k < 8; k++) sv[k] = ev;
    if (t < 256) hid[t] = 0.f;
    if (t < 128) tops[t] = empty_elem[t & 63];
    bnd[(w * 2) * 64 + lane] = ev;
    bnd[(w * 2 + 1) * 64 + lane] = ev;
    for (int i = t; i < 16384; i += 512) whs_l[i] = ws[WHST_OFF + i]; // [e][s]
    for (int i = t; i < 8192; i += 512) {
        int j = i >> 6, s = i & 63;
        wsu_l[(j >> 2) * 256 + s * 4 + (j & 3)] = ws[WSUT_OFF + i];
    }
    for (int i = t; i < 1024; i += 512)
        whaL[i] = (i < 768) ? W_ha[i] : W_hg[i - 768];
    __syncthreads();   // full barrier once (drains init global loads too)

    // ex double-buffer: preload step 0 (waves 4-7 own hid elem h = t-256)
    float exv = (w >= 4) ? out[(size_t)b * 256 + (t - 256)] : 0.f;

    const float* whsp = &whs_l[(w * 32) * 64 + lane];  // + e*64 per element

    for (int ts = 0; ts < T_STEPS; ts++) {
        // prefetch NEXT step's ex; with LDS-only barriers this load now has the
        // ENTIRE step (~2500cy) to cover its HBM latency instead of phase A only
        float exn = 0.f;
        if (w >= 4 && ts + 1 < T_STEPS)
            exn = out[((size_t)(ts + 1) * BATCH + b) * 256 + (t - 256)];

        // halo reads: neighbors' OLD boundary rows (published last step)
        float halo_lo = (w == 0) ? 0.f : bnd[((w - 1) * 2 + 1) * 64 + lane]; // row w*8-1
        float halo_hi = (w == 7) ? 0.f : bnd[((w + 1) * 2) * 64 + lane];     // row w*8+8

        // ======== phase A: all dot-product partials from old state
        float4 acc = make_float4(0.f, 0.f, 0.f, 0.f);
        float accP = 0.f, accU = 0.f;
#pragma unroll
        for (int eb = 0; eb < 8; eb++) {
            float4 hv = *(const float4*)&hid[w * 32 + eb * 4];
            acc.x = fmaf(whh[eb*4+0].x, hv.x, acc.x); acc.y = fmaf(whh[eb*4+0].y, hv.x, acc.y);
            acc.z = fmaf(whh[eb*4+0].z, hv.x, acc.z); acc.w = fmaf(whh[eb*4+0].w, hv.x, acc.w);
            acc.x = fmaf(whh[eb*4+1].x, hv.y, acc.x); acc.y = fmaf(whh[eb*4+1].y, hv.y, acc.y);
            acc.z = fmaf(whh[eb*4+1].z, hv.y, acc.z); acc.w = fmaf(whh[eb*4+1].w, hv.y, acc.w);
            acc.x = fmaf(whh[eb*4+2].x, hv.z, acc.x); acc.y = fmaf(whh[eb*4+2].y, hv.z, acc.y);
            acc.z = fmaf(whh[eb*4+2].z, hv.z, acc.z); acc.w = fmaf(whh[eb*4+2].w, hv.z, acc.w);
            acc.x = fmaf(whh[eb*4+3].x, hv.w, acc.x); acc.y = fmaf(whh[eb*4+3].y, hv.w, acc.y);
            acc.z = fmaf(whh[eb*4+3].z, hv.w, acc.z); acc.w = fmaf(whh[eb*4+3].w, hv.w, acc.w);
            accP = fmaf(whsp[(eb*4+0)*64], hv.x, accP);
            accP = fmaf(whsp[(eb*4+1)*64], hv.y, accP);
            accP = fmaf(whsp[(eb*4+2)*64], hv.z, accP);
            accP = fmaf(whsp[(eb*4+3)*64], hv.w, accP);
        }
#pragma unroll
        for (int jb = 0; jb < 4; jb++) {
            float4 tv = *(const float4*)&tops[w * 16 + jb * 4];
            acc.x = fmaf(wsh[jb*4+0].x, tv.x, acc.x); acc.y = fmaf(wsh[jb*4+0].y, tv.x, acc.y);
            acc.z = fmaf(wsh[jb*4+0].z, tv.x, acc.z); acc.w = fmaf(wsh[jb*4+0].w, tv.x, acc.w);
            acc.x = fmaf(wsh[jb*4+1].x, tv.y, acc.x); acc.y = fmaf(wsh[jb*4+1].y, tv.y, acc.y);
            acc.z = fmaf(wsh[jb*4+1].z, tv.y, acc.z); acc.w = fmaf(wsh[jb*4+1].w, tv.y, acc.w);
            acc.x = fmaf(wsh[jb*4+2].x, tv.z, acc.x); acc.y = fmaf(wsh[jb*4+2].y, tv.z, acc.y);
            acc.z = fmaf(wsh[jb*4+2].z, tv.z, acc.z); acc.w = fmaf(wsh[jb*4+2].w, tv.z, acc.w);
            acc.x = fmaf(wsh[jb*4+3].x, tv.w, acc.x); acc.y = fmaf(wsh[jb*4+3].y, tv.w, acc.y);
            acc.z = fmaf(wsh[jb*4+3].z, tv.w, acc.z); acc.w = fmaf(wsh[jb*4+3].w, tv.w, acc.w);
            float4 su = *(const float4*)&wsu_l[(w * 4 + jb) * 256 + lane * 4];
            accU = fmaf(su.x, tv.x, accU);
            accU = fmaf(su.y, tv.y, accU);
            accU = fmaf(su.z, tv.z, accU);
            accU = fmaf(su.w, tv.w, accU);
        }
        *(float4*)&partial[w * 256 + lane * 4] = acc;
        ppb[w * 64 + lane] = accP;
        pub[w * 64 + lane] = accU;

        // ======== phase B: act logits + gamma dots (waves 0..3, old hid)
        if (w < 4) {
            float bd = 0.f;
#pragma unroll
            for (int k = 0; k < 4; k++)
                bd = fmaf(whaL[w * 256 + k * 64 + lane], hid[k * 64 + lane], bd);
#pragma unroll
            for (int off = 32; off > 0; off >>= 1) bd += __shfl_down(bd, off);
            if (lane == 0) scal[w] = bd + bscal;
        }
        BAR_LDS(); // s1: partials + ppb/pub + scal visible; all old-state reads done

        // ---- wave 0 alone: push/pop values (only consumed by stack row 0)
        float pvv = 0.f, uvv = 0.f;
        if (w == 0) {
            float v1 = bhs_r, v2 = bsu_r;
#pragma unroll
            for (int q = 0; q < 8; q++) v1 += ppb[q * 64 + lane];
#pragma unroll
            for (int q = 0; q < 8; q++) v2 += pub[q * 64 + lane];
            pvv = fmaxf(v1, 0.f);
            uvv = fmaxf(v2, 0.f);
        }

        // ---- hid reduce (waves 4..7 own one h each)
        if (w >= 4) {
            int h = t - 256;
            float mh = exv;
#pragma unroll
            for (int q = 0; q < 8; q++) mh += partial[q * 256 + h];
            float nh = fmaxf(mh, 0.f);
            hid[h] = nh;
            out[((size_t)ts * BATCH + b) * 256 + h] = nh;
        }

        // ---- softmax -> sharpen (fast transcendentals; all threads redundant)
        float l0 = scal[0], l1 = scal[1], l2 = scal[2], gv = scal[3];
        float eg = __expf(gv);
        float g = 1.f + ((gv > 15.f) ? gv : __logf(1.f + eg));
        float m = fmaxf(l0, fmaxf(l1, l2));
        float z = __expf(l0 - m) + __expf(l1 - m) + __expf(l2 - m);
        float lz = __logf(z);
        float s0  = __expf(g * (l0 - m - lz));
        float s1v = __expf(g * (l1 - m - lz));
        float s2v = __expf(g * (l2 - m - lz));
        float S = s0 + s1v + s2v + 1e-16f;
        float rS = __builtin_amdgcn_rcpf(S);
        float p0 = s0 * rS, p1 = s1v * rS, p2 = s2v * rS;

        if (t == 0) {
            int am = 0; float bm = s0;
            if (s1v > bm) { bm = s1v; am = 1; }
            if (s2v > bm) { bm = s2v; am = 2; }
            out[ACTS_OFF + ts * BATCH + b] = (float)am;
        }

        // ---- stack blend fully in registers
        {
            float nv[8];
            float below0 = (w == 0) ? pvv : halo_lo;     // push src for row w*8
            float pop0   = (w == 0) ? uvv : sv[1];       // pop src (row 0 gets u_val)
            nv[0] = fmaf(p0, below0, fmaf(p1, pop0, p2 * sv[0]));
#pragma unroll
            for (int k = 1; k < 7; k++)
                nv[k] = fmaf(p0, sv[k - 1], fmaf(p1, sv[k + 1], p2 * sv[k]));
            nv[7] = fmaf(p0, sv[6], fmaf(p1, halo_hi, p2 * sv[7]));
#pragma unroll
            for (int k = 0; k < 8; k++) sv[k] = nv[k];
        }
        // publish new boundary rows (next step's "old" halo) + tops
        bnd[(w * 2) * 64 + lane] = sv[0];
        bnd[(w * 2 + 1) * 64 + lane] = sv[7];
        if (w == 0) { tops[lane] = sv[0]; tops[64 + lane] = sv[1]; }

        exv = exn;
        BAR_LDS(); // s2: new hid/tops/bnd visible for next step
    }

    // ---- final hid & stack
    if (t < 256) out[HID_OFF + (size_t)b * 256 + t] = hid[t];
#pragma unroll
    for (int k = 0; k < 8; k++)
        out[STACK_OFF + (size_t)b * 4096 + (w * 8 + k) * 64 + lane] = sv[k];
}

// ---------------- launcher ---------------------------------------------------
extern "C" void kernel_launch(void* const* d_in, const int* in_sizes, int n_in,
                              void* d_out, int out_size, void* d_ws, size_t ws_size,
                              hipStream_t stream)
{
    (void)in_sizes; (void)n_in; (void)out_size; (void)ws_size;
    const int*   inputs     = (const int*)d_in[0];
    const float* emb_W      = (const float*)d_in[1];
    const float* W_hh       = (const float*)d_in[2];
    const float* b_hh       = (const float*)d_in[3];
    const float* W_eh       = (const float*)d_in[4];
    const float* b_eh       = (const float*)d_in[5];
    const float* W_ha       = (const float*)d_in[6];
    const float* b_ha       = (const float*)d_in[7];
    const float* W_hg       = (const float*)d_in[8];
    const float* b_hg       = (const float*)d_in[9];
    const float* W_hs       = (const float*)d_in[10];
    const float* b_hs       = (const float*)d_in[11];
    const float* W_sh       = (const float*)d_in[12];
    const float* b_sh       = (const float*)d_in[13];
    const float* W_su       = (const float*)d_in[14];
    const float* b_su       = (const float*)d_in[15];
    const float* empty_elem = (const float*)d_in[16];
    float* out = (float*)d_out;
    float* ws  = (float*)d_ws;

    hipLaunchKernelGGL(prep_kernel, dim3(737), dim3(256), 0, stream,
                       W_hh, b_hh, W_eh, b_eh, W_sh, b_sh, W_hs, W_su, ws);
    hipLaunchKernelGGL(ex_gemm, dim3(1024), dim3(256), 0, stream,
                       inputs, emb_W, ws, out);
    hipLaunchKernelGGL(rnn_scan, dim3(128), dim3(512), 0, stream,
                       ws, W_ha, b_ha, W_hg, b_hg, b_hs, b_su, empty_elem, out);
}